// Round 1
// baseline (947.608 us; speedup 1.0000x reference)
//
#include <hip/hip_runtime.h>
#include <math.h>

// GIN: N=100000 nodes, E=1.6M edges, G=512 graphs, F_IN=128, H=64, L=3, C=2.
// Strategy: build CSR by dst (count/scan/fill), then per layer a fused
// kernel: wave = 2..4 nodes, lane = feature; aggregation gathers neighbor
// rows (coalesced 256/512B), MLP done with weights in LDS + per-wave LDS
// row broadcast. Pooling per graph (batch is sorted -> binary search), then
// tiny fused head.

#define NNODES 100000
#define NEDGES 1600000
#define NGRAPHS 512
#define NB_SCAN 98  // ceil(100000/1024)

// ---------------- CSR build ----------------

__global__ __launch_bounds__(256) void count_kernel(const int* __restrict__ dst,
                                                    int* __restrict__ cnt) {
  int e = blockIdx.x * 256 + threadIdx.x;
  if (e < NEDGES) atomicAdd(&cnt[dst[e]], 1);
}

__global__ __launch_bounds__(1024) void scan1(const int* __restrict__ cnt,
                                              int* __restrict__ row_ptr,
                                              int* __restrict__ bsum) {
  __shared__ int sd[1024];
  int t = threadIdx.x;
  int i = blockIdx.x * 1024 + t;
  int v = (i < NNODES) ? cnt[i] : 0;
  sd[t] = v;
  __syncthreads();
  for (int off = 1; off < 1024; off <<= 1) {
    int u = (t >= off) ? sd[t - off] : 0;
    __syncthreads();
    sd[t] += u;
    __syncthreads();
  }
  if (i < NNODES) row_ptr[i + 1] = sd[t];
  if (t == 1023) bsum[blockIdx.x] = sd[1023];
  if (i == 0) row_ptr[0] = 0;
}

__global__ __launch_bounds__(128) void scan2(const int* __restrict__ bsum,
                                             int* __restrict__ boff, int nb) {
  __shared__ int sd[128];
  int t = threadIdx.x;
  int v = (t < nb) ? bsum[t] : 0;
  sd[t] = v;
  __syncthreads();
  for (int off = 1; off < 128; off <<= 1) {
    int u = (t >= off) ? sd[t - off] : 0;
    __syncthreads();
    sd[t] += u;
    __syncthreads();
  }
  if (t < nb) boff[t] = sd[t] - v;  // exclusive
}

__global__ __launch_bounds__(1024) void scan3(int* __restrict__ row_ptr,
                                              const int* __restrict__ boff,
                                              int* __restrict__ cur) {
  int i = blockIdx.x * 1024 + threadIdx.x;
  if (i < NNODES) {
    int v = row_ptr[i + 1] + boff[blockIdx.x];
    row_ptr[i + 1] = v;
    if (i + 1 < NNODES) cur[i + 1] = v;
  }
  if (i == 0) cur[0] = 0;
}

__global__ __launch_bounds__(256) void fill_kernel(const int* __restrict__ src,
                                                   const int* __restrict__ dst,
                                                   int* __restrict__ cur,
                                                   int* __restrict__ col) {
  int e = blockIdx.x * 256 + threadIdx.x;
  if (e < NEDGES) {
    int d = dst[e];
    int p = atomicAdd(&cur[d], 1);
    col[p] = src[e];
  }
}

// ---------------- Layer 0: F_IN=128 -> 64 -> 64, 2 nodes per wave ----------------

__global__ __launch_bounds__(512) void layer0_kernel(
    const float* __restrict__ xin, const float* __restrict__ w1,
    const float* __restrict__ b1, const float* __restrict__ w2,
    const float* __restrict__ b2, const float* __restrict__ eps,
    const int* __restrict__ row_ptr, const int* __restrict__ col,
    float* __restrict__ hout) {
  __shared__ float w1s[128 * 64];
  __shared__ float w2s[64 * 64];
  __shared__ float b1s[64], b2s[64];
  __shared__ float rows[8][256];  // per-wave row slab (128 feats x 2 nodes)
  int tid = threadIdx.x;
  for (int i = tid; i < 128 * 64; i += 512) w1s[i] = w1[i];
  for (int i = tid; i < 64 * 64; i += 512) w2s[i] = w2[i];
  if (tid < 64) {
    b1s[tid] = b1[tid];
    b2s[tid] = b2[tid];
  }
  __syncthreads();
  const float e1 = 1.0f + eps[0];
  const int lane = tid & 63;
  const int wv = tid >> 6;
  float* myrows = rows[wv];
  const int n0 = (blockIdx.x * 8 + wv) * 2;  // grid sized exactly: n0+1 < N

  float2 a0 = {0.f, 0.f}, a1 = {0.f, 0.f};
  {
    int rs = row_ptr[n0], re = row_ptr[n0 + 1];
    int e = rs;
    for (; e + 2 <= re; e += 2) {
      int s0 = col[e], s1 = col[e + 1];
      float2 v0 = *(const float2*)&xin[s0 * 128 + 2 * lane];
      float2 v1 = *(const float2*)&xin[s1 * 128 + 2 * lane];
      a0.x += v0.x + v1.x;
      a0.y += v0.y + v1.y;
    }
    if (e < re) {
      float2 v = *(const float2*)&xin[col[e] * 128 + 2 * lane];
      a0.x += v.x;
      a0.y += v.y;
    }
    float2 xv = *(const float2*)&xin[n0 * 128 + 2 * lane];
    a0.x += e1 * xv.x;
    a0.y += e1 * xv.y;
  }
  {
    int n = n0 + 1;
    int rs = row_ptr[n], re = row_ptr[n + 1];
    int e = rs;
    for (; e + 2 <= re; e += 2) {
      int s0 = col[e], s1 = col[e + 1];
      float2 v0 = *(const float2*)&xin[s0 * 128 + 2 * lane];
      float2 v1 = *(const float2*)&xin[s1 * 128 + 2 * lane];
      a1.x += v0.x + v1.x;
      a1.y += v0.y + v1.y;
    }
    if (e < re) {
      float2 v = *(const float2*)&xin[col[e] * 128 + 2 * lane];
      a1.x += v.x;
      a1.y += v.y;
    }
    float2 xv = *(const float2*)&xin[n * 128 + 2 * lane];
    a1.x += e1 * xv.x;
    a1.y += e1 * xv.y;
  }
  // rows[k*2 + j] = row_j[k]; lane owns features 2*lane, 2*lane+1
  float4 pk = {a0.x, a1.x, a0.y, a1.y};
  *(float4*)&myrows[lane * 4] = pk;
  __asm__ volatile("s_waitcnt lgkmcnt(0)" ::: "memory");

  float acc0 = b1s[lane], acc1 = b1s[lane];
#pragma unroll
  for (int k = 0; k < 128; ++k) {
    float2 r = *(const float2*)&myrows[k * 2];  // broadcast
    float w = w1s[k * 64 + lane];               // stride-1, conflict-free
    acc0 += r.x * w;
    acc1 += r.y * w;
  }
  acc0 = fmaxf(acc0, 0.f);
  acc1 = fmaxf(acc1, 0.f);

  float2 h2 = {acc0, acc1};
  *(float2*)&myrows[lane * 2] = h2;
  __asm__ volatile("s_waitcnt lgkmcnt(0)" ::: "memory");

  float o0 = b2s[lane], o1 = b2s[lane];
#pragma unroll
  for (int k = 0; k < 64; ++k) {
    float2 r = *(const float2*)&myrows[k * 2];
    float w = w2s[k * 64 + lane];
    o0 += r.x * w;
    o1 += r.y * w;
  }
  hout[n0 * 64 + lane] = fmaxf(o0, 0.f);
  hout[(n0 + 1) * 64 + lane] = fmaxf(o1, 0.f);
}

// ---------------- Layers 1/2: 64 -> 64 -> 64, 4 nodes per wave ----------------

__global__ __launch_bounds__(512) void layer64_kernel(
    const float* __restrict__ xin, const float* __restrict__ w1,
    const float* __restrict__ b1, const float* __restrict__ w2,
    const float* __restrict__ b2, const float* __restrict__ eps, int li,
    const int* __restrict__ row_ptr, const int* __restrict__ col,
    float* __restrict__ hout) {
  __shared__ float w1s[64 * 64];
  __shared__ float w2s[64 * 64];
  __shared__ float b1s[64], b2s[64];
  __shared__ float rows[8][256];  // 64 feats x 4 nodes per wave
  int tid = threadIdx.x;
  for (int i = tid; i < 64 * 64; i += 512) {
    w1s[i] = w1[i];
    w2s[i] = w2[i];
  }
  if (tid < 64) {
    b1s[tid] = b1[tid];
    b2s[tid] = b2[tid];
  }
  __syncthreads();
  const float e1 = 1.0f + eps[li];
  const int lane = tid & 63;
  const int wv = tid >> 6;
  float* myrows = rows[wv];
  const int n0 = (blockIdx.x * 8 + wv) * 4;  // grid exact: n0+3 < N

  float a[4];
#pragma unroll
  for (int j = 0; j < 4; ++j) {
    int n = n0 + j;
    int rs = row_ptr[n], re = row_ptr[n + 1];
    float s = 0.f;
    int e = rs;
    for (; e + 2 <= re; e += 2) {
      int s0 = col[e], s1 = col[e + 1];
      s += xin[s0 * 64 + lane] + xin[s1 * 64 + lane];
    }
    if (e < re) s += xin[col[e] * 64 + lane];
    a[j] = s + e1 * xin[n * 64 + lane];
  }
  float4 pk = {a[0], a[1], a[2], a[3]};
  *(float4*)&myrows[lane * 4] = pk;
  __asm__ volatile("s_waitcnt lgkmcnt(0)" ::: "memory");

  float acc[4];
#pragma unroll
  for (int j = 0; j < 4; ++j) acc[j] = b1s[lane];
#pragma unroll
  for (int k = 0; k < 64; ++k) {
    float4 r = *(const float4*)&myrows[k * 4];  // broadcast
    float w = w1s[k * 64 + lane];
    acc[0] += r.x * w;
    acc[1] += r.y * w;
    acc[2] += r.z * w;
    acc[3] += r.w * w;
  }
#pragma unroll
  for (int j = 0; j < 4; ++j) acc[j] = fmaxf(acc[j], 0.f);

  float4 hk = {acc[0], acc[1], acc[2], acc[3]};
  *(float4*)&myrows[lane * 4] = hk;
  __asm__ volatile("s_waitcnt lgkmcnt(0)" ::: "memory");

  float o[4];
#pragma unroll
  for (int j = 0; j < 4; ++j) o[j] = b2s[lane];
#pragma unroll
  for (int k = 0; k < 64; ++k) {
    float4 r = *(const float4*)&myrows[k * 4];
    float w = w2s[k * 64 + lane];
    o[0] += r.x * w;
    o[1] += r.y * w;
    o[2] += r.z * w;
    o[3] += r.w * w;
  }
#pragma unroll
  for (int j = 0; j < 4; ++j) hout[(n0 + j) * 64 + lane] = fmaxf(o[j], 0.f);
}

// ---------------- Per-graph pooling (batch sorted) ----------------

__device__ __forceinline__ int lower_bound(const int* __restrict__ a, int n,
                                           int v) {
  int lo = 0, hi = n;
  while (lo < hi) {
    int m = (lo + hi) >> 1;
    if (a[m] < v)
      lo = m + 1;
    else
      hi = m;
  }
  return lo;
}

__global__ __launch_bounds__(256) void pool_kernel(const float* __restrict__ h,
                                                   const int* __restrict__ batch,
                                                   float* __restrict__ g,
                                                   int li) {
  int gi = blockIdx.x;
  int tid = threadIdx.x;
  int sub = tid >> 6, f = tid & 63;
  int s = lower_bound(batch, NNODES, gi);
  int e = lower_bound(batch, NNODES, gi + 1);
  float sum = 0.f, mx = -3.0e38f;
  for (int n = s + sub; n < e; n += 4) {
    float v = h[n * 64 + f];
    sum += v;
    mx = fmaxf(mx, v);
  }
  __shared__ float ssum[4][64];
  __shared__ float smax[4][64];
  ssum[sub][f] = sum;
  smax[sub][f] = mx;
  __syncthreads();
  if (tid < 64) {
    float S = ssum[0][f] + ssum[1][f] + ssum[2][f] + ssum[3][f];
    float M = fmaxf(fmaxf(smax[0][f], smax[1][f]), fmaxf(smax[2][f], smax[3][f]));
    int cnt = e - s;
    float mean = S / fmaxf((float)cnt, 1.0f);
    int base = gi * 576 + li * 64 + f;
    g[base] = mean;           // mean block: cols [0,192)
    g[base + 192] = M;        // max block:  cols [192,384)
    g[base + 384] = S;        // sum block:  cols [384,576)
  }
}

// ---------------- Head: g[512,576] @ fc1 -> relu -> @ fc2 -> sigmoid ----------------

__global__ __launch_bounds__(256) void head_kernel(
    const float* __restrict__ g, const float* __restrict__ fc1w,
    const float* __restrict__ fc1b, const float* __restrict__ fc2w,
    const float* __restrict__ fc2b, float* __restrict__ out) {
  __shared__ float gs[4 * 576];
  int tid = threadIdx.x;
  int g0 = blockIdx.x * 4;
  for (int i = tid; i < 4 * 576; i += 256) gs[i] = g[g0 * 576 + i];
  __syncthreads();
  int wv = tid >> 6, lane = tid & 63;
  int gi = g0 + wv;
  const float* grow = &gs[wv * 576];
  float acc = fc1b[lane];
#pragma unroll 8
  for (int k = 0; k < 576; ++k) acc += grow[k] * fc1w[k * 64 + lane];
  acc = fmaxf(acc, 0.f);
  float p0 = acc * fc2w[lane * 2 + 0];
  float p1 = acc * fc2w[lane * 2 + 1];
  for (int off = 32; off; off >>= 1) {
    p0 += __shfl_down(p0, off);
    p1 += __shfl_down(p1, off);
  }
  if (lane == 0) {
    out[gi * 2 + 0] = 1.f / (1.f + __expf(-(p0 + fc2b[0])));
    out[gi * 2 + 1] = 1.f / (1.f + __expf(-(p1 + fc2b[1])));
  }
}

// ---------------- launch ----------------

extern "C" void kernel_launch(void* const* d_in, const int* in_sizes, int n_in,
                              void* d_out, int out_size, void* d_ws,
                              size_t ws_size, hipStream_t stream) {
  const float* x = (const float*)d_in[0];
  const int* ei = (const int*)d_in[1];
  const int* src = ei;
  const int* dst = ei + NEDGES;
  const int* batch = (const int*)d_in[2];
  const float* lw1[3] = {(const float*)d_in[3], (const float*)d_in[7],
                         (const float*)d_in[11]};
  const float* lb1[3] = {(const float*)d_in[4], (const float*)d_in[8],
                         (const float*)d_in[12]};
  const float* lw2[3] = {(const float*)d_in[5], (const float*)d_in[9],
                         (const float*)d_in[13]};
  const float* lb2[3] = {(const float*)d_in[6], (const float*)d_in[10],
                         (const float*)d_in[14]};
  const float* eps = (const float*)d_in[15];
  const float* fc1w = (const float*)d_in[16];
  const float* fc1b = (const float*)d_in[17];
  const float* fc2w = (const float*)d_in[18];
  const float* fc2b = (const float*)d_in[19];
  float* out = (float*)d_out;

  char* p = (char*)d_ws;
  auto carve = [&](size_t bytes) {
    void* r = (void*)p;
    p += (bytes + 1023) & ~(size_t)1023;
    return r;
  };
  int* cnt = (int*)carve((NNODES + 4) * 4);
  int* row_ptr = (int*)carve((NNODES + 4) * 4);
  int* cur = (int*)carve((NNODES + 4) * 4);
  int* bsum = (int*)carve(1024);
  int* boff = (int*)carve(1024);
  int* col = (int*)carve((size_t)NEDGES * 4);
  float* hA = (float*)carve((size_t)NNODES * 64 * 4);
  float* hB = (float*)carve((size_t)NNODES * 64 * 4);
  float* g = (float*)carve((size_t)NGRAPHS * 576 * 4);

  hipMemsetAsync(cnt, 0, (NNODES + 1) * 4, stream);
  count_kernel<<<(NEDGES + 255) / 256, 256, 0, stream>>>(dst, cnt);
  scan1<<<NB_SCAN, 1024, 0, stream>>>(cnt, row_ptr, bsum);
  scan2<<<1, 128, 0, stream>>>(bsum, boff, NB_SCAN);
  scan3<<<NB_SCAN, 1024, 0, stream>>>(row_ptr, boff, cur);
  fill_kernel<<<(NEDGES + 255) / 256, 256, 0, stream>>>(src, dst, cur, col);

  // layer 0: 8 waves/block * 2 nodes = 16 nodes/block -> 6250 blocks exact
  layer0_kernel<<<6250, 512, 0, stream>>>(x, lw1[0], lb1[0], lw2[0], lb2[0],
                                          eps, row_ptr, col, hA);
  pool_kernel<<<NGRAPHS, 256, 0, stream>>>(hA, batch, g, 0);
  // layers 1/2: 8 waves * 4 nodes = 32 nodes/block -> 3125 blocks exact
  layer64_kernel<<<3125, 512, 0, stream>>>(hA, lw1[1], lb1[1], lw2[1], lb2[1],
                                           eps, 1, row_ptr, col, hB);
  pool_kernel<<<NGRAPHS, 256, 0, stream>>>(hB, batch, g, 1);
  layer64_kernel<<<3125, 512, 0, stream>>>(hB, lw1[2], lb1[2], lw2[2], lb2[2],
                                           eps, 2, row_ptr, col, hA);
  pool_kernel<<<NGRAPHS, 256, 0, stream>>>(hA, batch, g, 2);

  head_kernel<<<NGRAPHS / 4, 256, 0, stream>>>(g, fc1w, fc1b, fc2w, fc2b, out);
}

// Round 2
// 767.727 us; speedup vs baseline: 1.2343x; 1.2343x over previous
//
#include <hip/hip_runtime.h>
#include <math.h>

// GIN restructured: aggregation commutes with the first linear layer.
//   h = relu(((1+eps)x + agg_x) @ w1 + b1) = relu((1+eps)z + agg_z + b1),  z = x@w1
// Pipeline:
//   gemm128: zA = x @ l0_w1                       (N x 128 -> N x 64)
//   agg<HAS_NEXT>: gather z rows (256B/edge), h1 = relu((1+eps)z+agg+b1),
//                  h = relu(h1@w2+b2)  -> hout (for pooling)
//                  znext = h @ w1_next -> zn    (fused next-layer transform)
//   pool per graph (batch sorted), fused head.

#define NNODES 100000
#define NEDGES 1600000
#define NGRAPHS 512
#define NB_SCAN 98  // ceil(100000/1024)

// ---------------- CSR build ----------------

__global__ __launch_bounds__(256) void count_kernel(const int* __restrict__ dst,
                                                    int* __restrict__ cnt) {
  int e = blockIdx.x * 256 + threadIdx.x;
  if (e < NEDGES) atomicAdd(&cnt[dst[e]], 1);
}

__global__ __launch_bounds__(1024) void scan1(const int* __restrict__ cnt,
                                              int* __restrict__ row_ptr,
                                              int* __restrict__ bsum) {
  __shared__ int sd[1024];
  int t = threadIdx.x;
  int i = blockIdx.x * 1024 + t;
  int v = (i < NNODES) ? cnt[i] : 0;
  sd[t] = v;
  __syncthreads();
  for (int off = 1; off < 1024; off <<= 1) {
    int u = (t >= off) ? sd[t - off] : 0;
    __syncthreads();
    sd[t] += u;
    __syncthreads();
  }
  if (i < NNODES) row_ptr[i + 1] = sd[t];
  if (t == 1023) bsum[blockIdx.x] = sd[1023];
  if (i == 0) row_ptr[0] = 0;
}

__global__ __launch_bounds__(128) void scan2(const int* __restrict__ bsum,
                                             int* __restrict__ boff, int nb) {
  __shared__ int sd[128];
  int t = threadIdx.x;
  int v = (t < nb) ? bsum[t] : 0;
  sd[t] = v;
  __syncthreads();
  for (int off = 1; off < 128; off <<= 1) {
    int u = (t >= off) ? sd[t - off] : 0;
    __syncthreads();
    sd[t] += u;
    __syncthreads();
  }
  if (t < nb) boff[t] = sd[t] - v;  // exclusive
}

__global__ __launch_bounds__(1024) void scan3(int* __restrict__ row_ptr,
                                              const int* __restrict__ boff,
                                              int* __restrict__ cur) {
  int i = blockIdx.x * 1024 + threadIdx.x;
  if (i < NNODES) {
    int v = row_ptr[i + 1] + boff[blockIdx.x];
    row_ptr[i + 1] = v;
    if (i + 1 < NNODES) cur[i + 1] = v;
  }
  if (i == 0) cur[0] = 0;
}

__global__ __launch_bounds__(256) void fill_kernel(const int* __restrict__ src,
                                                   const int* __restrict__ dst,
                                                   int* __restrict__ cur,
                                                   int* __restrict__ col) {
  int e = blockIdx.x * 256 + threadIdx.x;
  if (e < NEDGES) {
    int d = dst[e];
    int p = atomicAdd(&cur[d], 1);
    col[p] = src[e];
  }
}

// ---------------- GEMM: z = x(Nx128) @ w1(128x64) ----------------
// 8 waves/block, 4 nodes/wave -> 32 nodes/block, 3125 blocks exact.

__global__ __launch_bounds__(512) void gemm128_kernel(
    const float* __restrict__ x, const float* __restrict__ w1,
    float* __restrict__ z) {
  __shared__ float w1s[128 * 64];     // 32 KB
  __shared__ float rows[8][128 * 4];  // 16 KB: rows[wv][k*4+j]
  int tid = threadIdx.x;
  for (int i = tid; i < 128 * 64; i += 512) w1s[i] = w1[i];
  __syncthreads();
  const int lane = tid & 63;
  const int wv = tid >> 6;
  float* myrows = rows[wv];
  const int n0 = (blockIdx.x * 8 + wv) * 4;

  // stage 4 node rows: lane owns k=lane and k=64+lane; float4 across j
  float lo[4], hi[4];
#pragma unroll
  for (int j = 0; j < 4; ++j) {
    lo[j] = x[(size_t)(n0 + j) * 128 + lane];
    hi[j] = x[(size_t)(n0 + j) * 128 + 64 + lane];
  }
  *(float4*)&myrows[lane * 4] = make_float4(lo[0], lo[1], lo[2], lo[3]);
  *(float4*)&myrows[(64 + lane) * 4] = make_float4(hi[0], hi[1], hi[2], hi[3]);
  __asm__ volatile("s_waitcnt lgkmcnt(0)" ::: "memory");

  float acc[4] = {0.f, 0.f, 0.f, 0.f};
#pragma unroll 8
  for (int k = 0; k < 128; ++k) {
    float4 r = *(const float4*)&myrows[k * 4];  // broadcast
    float w = w1s[k * 64 + lane];               // stride-1 (2-way, free)
    acc[0] += r.x * w;
    acc[1] += r.y * w;
    acc[2] += r.z * w;
    acc[3] += r.w * w;
  }
#pragma unroll
  for (int j = 0; j < 4; ++j) z[(size_t)(n0 + j) * 64 + lane] = acc[j];
}

// ---------------- Fused agg + MLP (+ next transform) ----------------
// wave = 4 nodes, lane = feature. 8 waves/block, 3125 blocks exact.

template <bool HAS_NEXT>
__global__ __launch_bounds__(512) void agg_kernel(
    const float* __restrict__ zin, const float* __restrict__ b1,
    const float* __restrict__ w2, const float* __restrict__ b2,
    const float* __restrict__ w1n, const float* __restrict__ eps, int li,
    const int* __restrict__ row_ptr, const int* __restrict__ col,
    float* __restrict__ hout, float* __restrict__ zn) {
  __shared__ float w2s[64 * 64];  // 16 KB
  __shared__ float w1ns[HAS_NEXT ? 64 * 64 : 1];
  __shared__ float b1s[64], b2s[64];
  __shared__ float rows[8][256];  // 8 KB
  int tid = threadIdx.x;
  for (int i = tid; i < 64 * 64; i += 512) {
    w2s[i] = w2[i];
    if (HAS_NEXT) w1ns[i] = w1n[i];
  }
  if (tid < 64) {
    b1s[tid] = b1[tid];
    b2s[tid] = b2[tid];
  }
  __syncthreads();
  const float e1 = 1.0f + eps[li];
  const int lane = tid & 63;
  const int wv = tid >> 6;
  float* myrows = rows[wv];
  const int n0 = (blockIdx.x * 8 + wv) * 4;

  float a[4];
#pragma unroll
  for (int j = 0; j < 4; ++j) {
    int n = n0 + j;
    int rs = row_ptr[n], re = row_ptr[n + 1];
    float s0 = 0.f, s1 = 0.f, s2 = 0.f, s3 = 0.f;
    int e = rs;
    for (; e + 4 <= re; e += 4) {
      int c0 = col[e], c1 = col[e + 1], c2 = col[e + 2], c3 = col[e + 3];
      s0 += zin[(size_t)c0 * 64 + lane];
      s1 += zin[(size_t)c1 * 64 + lane];
      s2 += zin[(size_t)c2 * 64 + lane];
      s3 += zin[(size_t)c3 * 64 + lane];
    }
    for (; e < re; ++e) s0 += zin[(size_t)col[e] * 64 + lane];
    a[j] = (s0 + s1) + (s2 + s3) + e1 * zin[(size_t)n * 64 + lane];
  }
  // h1 = relu(a + b1); stage rows[k=lane][j] as float4
  float bb = b1s[lane];
#pragma unroll
  for (int j = 0; j < 4; ++j) a[j] = fmaxf(a[j] + bb, 0.f);
  *(float4*)&myrows[lane * 4] = make_float4(a[0], a[1], a[2], a[3]);
  __asm__ volatile("s_waitcnt lgkmcnt(0)" ::: "memory");

  float o[4];
  float b2v = b2s[lane];
#pragma unroll
  for (int j = 0; j < 4; ++j) o[j] = b2v;
#pragma unroll 8
  for (int k = 0; k < 64; ++k) {
    float4 r = *(const float4*)&myrows[k * 4];  // broadcast
    float w = w2s[k * 64 + lane];
    o[0] += r.x * w;
    o[1] += r.y * w;
    o[2] += r.z * w;
    o[3] += r.w * w;
  }
#pragma unroll
  for (int j = 0; j < 4; ++j) {
    o[j] = fmaxf(o[j], 0.f);
    hout[(size_t)(n0 + j) * 64 + lane] = o[j];
  }

  if (HAS_NEXT) {
    *(float4*)&myrows[lane * 4] = make_float4(o[0], o[1], o[2], o[3]);
    __asm__ volatile("s_waitcnt lgkmcnt(0)" ::: "memory");
    float q[4] = {0.f, 0.f, 0.f, 0.f};
#pragma unroll 8
    for (int k = 0; k < 64; ++k) {
      float4 r = *(const float4*)&myrows[k * 4];
      float w = w1ns[k * 64 + lane];
      q[0] += r.x * w;
      q[1] += r.y * w;
      q[2] += r.z * w;
      q[3] += r.w * w;
    }
#pragma unroll
    for (int j = 0; j < 4; ++j) zn[(size_t)(n0 + j) * 64 + lane] = q[j];
  }
}

// ---------------- Per-graph pooling (batch sorted) ----------------

__device__ __forceinline__ int lower_bound(const int* __restrict__ a, int n,
                                           int v) {
  int lo = 0, hi = n;
  while (lo < hi) {
    int m = (lo + hi) >> 1;
    if (a[m] < v)
      lo = m + 1;
    else
      hi = m;
  }
  return lo;
}

__global__ __launch_bounds__(256) void pool_kernel(const float* __restrict__ h,
                                                   const int* __restrict__ batch,
                                                   float* __restrict__ g,
                                                   int li) {
  int gi = blockIdx.x;
  int tid = threadIdx.x;
  int sub = tid >> 6, f = tid & 63;
  int s = lower_bound(batch, NNODES, gi);
  int e = lower_bound(batch, NNODES, gi + 1);
  float sum = 0.f, mx = -3.0e38f;
  for (int n = s + sub; n < e; n += 4) {
    float v = h[(size_t)n * 64 + f];
    sum += v;
    mx = fmaxf(mx, v);
  }
  __shared__ float ssum[4][64];
  __shared__ float smax[4][64];
  ssum[sub][f] = sum;
  smax[sub][f] = mx;
  __syncthreads();
  if (tid < 64) {
    float S = ssum[0][f] + ssum[1][f] + ssum[2][f] + ssum[3][f];
    float M = fmaxf(fmaxf(smax[0][f], smax[1][f]), fmaxf(smax[2][f], smax[3][f]));
    int cnt = e - s;
    float mean = S / fmaxf((float)cnt, 1.0f);
    int base = gi * 576 + li * 64 + f;
    g[base] = mean;     // mean cols [0,192)
    g[base + 192] = M;  // max cols [192,384)
    g[base + 384] = S;  // sum cols [384,576)
  }
}

// ---------------- Head ----------------

__global__ __launch_bounds__(256) void head_kernel(
    const float* __restrict__ g, const float* __restrict__ fc1w,
    const float* __restrict__ fc1b, const float* __restrict__ fc2w,
    const float* __restrict__ fc2b, float* __restrict__ out) {
  __shared__ float gs[4 * 576];
  int tid = threadIdx.x;
  int g0 = blockIdx.x * 4;
  for (int i = tid; i < 4 * 576; i += 256) gs[i] = g[g0 * 576 + i];
  __syncthreads();
  int wv = tid >> 6, lane = tid & 63;
  int gi = g0 + wv;
  const float* grow = &gs[wv * 576];
  float acc = fc1b[lane];
#pragma unroll 8
  for (int k = 0; k < 576; ++k) acc += grow[k] * fc1w[k * 64 + lane];
  acc = fmaxf(acc, 0.f);
  float p0 = acc * fc2w[lane * 2 + 0];
  float p1 = acc * fc2w[lane * 2 + 1];
  for (int off = 32; off; off >>= 1) {
    p0 += __shfl_down(p0, off);
    p1 += __shfl_down(p1, off);
  }
  if (lane == 0) {
    out[gi * 2 + 0] = 1.f / (1.f + __expf(-(p0 + fc2b[0])));
    out[gi * 2 + 1] = 1.f / (1.f + __expf(-(p1 + fc2b[1])));
  }
}

// ---------------- launch ----------------

extern "C" void kernel_launch(void* const* d_in, const int* in_sizes, int n_in,
                              void* d_out, int out_size, void* d_ws,
                              size_t ws_size, hipStream_t stream) {
  const float* x = (const float*)d_in[0];
  const int* ei = (const int*)d_in[1];
  const int* src = ei;
  const int* dst = ei + NEDGES;
  const int* batch = (const int*)d_in[2];
  const float* lw1[3] = {(const float*)d_in[3], (const float*)d_in[7],
                         (const float*)d_in[11]};
  const float* lb1[3] = {(const float*)d_in[4], (const float*)d_in[8],
                         (const float*)d_in[12]};
  const float* lw2[3] = {(const float*)d_in[5], (const float*)d_in[9],
                         (const float*)d_in[13]};
  const float* lb2[3] = {(const float*)d_in[6], (const float*)d_in[10],
                         (const float*)d_in[14]};
  const float* eps = (const float*)d_in[15];
  const float* fc1w = (const float*)d_in[16];
  const float* fc1b = (const float*)d_in[17];
  const float* fc2w = (const float*)d_in[18];
  const float* fc2b = (const float*)d_in[19];
  float* out = (float*)d_out;

  char* p = (char*)d_ws;
  auto carve = [&](size_t bytes) {
    void* r = (void*)p;
    p += (bytes + 1023) & ~(size_t)1023;
    return r;
  };
  int* cnt = (int*)carve((NNODES + 4) * 4);
  int* row_ptr = (int*)carve((NNODES + 4) * 4);
  int* cur = (int*)carve((NNODES + 4) * 4);
  int* bsum = (int*)carve(1024);
  int* boff = (int*)carve(1024);
  int* col = (int*)carve((size_t)NEDGES * 4);
  float* zA = (float*)carve((size_t)NNODES * 64 * 4);
  float* zB = (float*)carve((size_t)NNODES * 64 * 4);
  float* hA = (float*)carve((size_t)NNODES * 64 * 4);
  float* g = (float*)carve((size_t)NGRAPHS * 576 * 4);

  hipMemsetAsync(cnt, 0, (NNODES + 1) * 4, stream);
  count_kernel<<<(NEDGES + 255) / 256, 256, 0, stream>>>(dst, cnt);
  scan1<<<NB_SCAN, 1024, 0, stream>>>(cnt, row_ptr, bsum);
  scan2<<<1, 128, 0, stream>>>(bsum, boff, NB_SCAN);
  scan3<<<NB_SCAN, 1024, 0, stream>>>(row_ptr, boff, cur);
  fill_kernel<<<(NEDGES + 255) / 256, 256, 0, stream>>>(src, dst, cur, col);

  // z0 = x @ l0_w1
  gemm128_kernel<<<3125, 512, 0, stream>>>(x, lw1[0], zA);

  // layer 0: h0 -> hA (pool), z1 = h0 @ l1_w1 -> zB
  agg_kernel<true><<<3125, 512, 0, stream>>>(zA, lb1[0], lw2[0], lb2[0],
                                             lw1[1], eps, 0, row_ptr, col, hA,
                                             zB);
  pool_kernel<<<NGRAPHS, 256, 0, stream>>>(hA, batch, g, 0);

  // layer 1: h1 -> hA (pool0 done, stream-serial), z2 -> zA (z0 dead)
  agg_kernel<true><<<3125, 512, 0, stream>>>(zB, lb1[1], lw2[1], lb2[1],
                                             lw1[2], eps, 1, row_ptr, col, hA,
                                             zA);
  pool_kernel<<<NGRAPHS, 256, 0, stream>>>(hA, batch, g, 1);

  // layer 2: h2 -> hA, no next transform
  agg_kernel<false><<<3125, 512, 0, stream>>>(zA, lb1[2], lw2[2], lb2[2],
                                              (const float*)nullptr, eps, 2,
                                              row_ptr, col, hA, (float*)nullptr);
  pool_kernel<<<NGRAPHS, 256, 0, stream>>>(hA, batch, g, 2);

  head_kernel<<<NGRAPHS / 4, 256, 0, stream>>>(g, fc1w, fc1b, fc2w, fc2b, out);
}

// Round 3
// 609.245 us; speedup vs baseline: 1.5554x; 1.2601x over previous
//
#include <hip/hip_runtime.h>
#include <math.h>

// GIN: agg commutes with first linear -> z = x@w1 precomputed; per layer:
//   h = relu(relu((1+eps)z + sum_j z_j + b1) @ w2 + b2), znext = h @ w1next.
// Edge grouping: one-pass LDS-binned scatter into 782 buckets of 128 dst
// nodes (packed (src<<7)|dst_local, 4B/edge). Agg kernel = 1 bucket/block:
// local CSR in LDS, gather z rows, fused MLP (+next transform).

#define NNODES 100000
#define NEDGES 1600000
#define NGRAPHS 512
#define NB 782     // ceil(100000/128)
#define BCAP 2560  // per-bucket capacity (mean 2046, sd ~45)
#define CHUNK 8192
#define NCHUNKS 196  // ceil(1600000/8192)

// ---------------- bucket init ----------------

__global__ __launch_bounds__(256) void init_gcur(int* __restrict__ gcur) {
  int i = blockIdx.x * 256 + threadIdx.x;
  if (i < NB) gcur[i] = i * BCAP;
}

// ---------------- binned scatter: edges -> bucket-grouped staging ----------------

__global__ __launch_bounds__(512) void bin_kernel(const int* __restrict__ src,
                                                  const int* __restrict__ dst,
                                                  int* __restrict__ gcur,
                                                  int* __restrict__ st) {
  __shared__ int hist[NB];
  __shared__ int lofs[NB + 1];
  __shared__ int lcur[NB];
  __shared__ int gbase[NB];
  __shared__ int sd[1024];
  __shared__ int staged[CHUNK];
  const int t = threadIdx.x;
  const int e0 = blockIdx.x * CHUNK;
  const int n = min(CHUNK, NEDGES - e0);

  for (int i = t; i < NB; i += 512) hist[i] = 0;
  __syncthreads();

  int pk[16];
  int bk[16];
#pragma unroll
  for (int k = 0; k < 16; ++k) {
    int i = t + k * 512;
    if (i < n) {
      int s = src[e0 + i];
      int d = dst[e0 + i];
      int b = d >> 7;
      pk[k] = (s << 7) | (d & 127);
      bk[k] = b;
      atomicAdd(&hist[b], 1);
    } else {
      bk[k] = -1;
    }
  }
  __syncthreads();

  // inclusive scan of hist (782) via 2 elems/thread Hillis-Steele
  sd[t] = (t < NB) ? hist[t] : 0;
  sd[t + 512] = (t + 512 < NB) ? hist[t + 512] : 0;
  __syncthreads();
  for (int off = 1; off < 1024; off <<= 1) {
    int v0 = (t >= off) ? sd[t - off] : 0;
    int v1 = (t + 512 >= off) ? sd[t + 512 - off] : 0;
    __syncthreads();
    sd[t] += v0;
    sd[t + 512] += v1;
    __syncthreads();
  }
  if (t == 0) lofs[0] = 0;
  for (int i = t; i < NB; i += 512) {
    int inc = sd[i];
    int c = hist[i];
    lofs[i + 1] = inc;
    lcur[i] = inc - c;  // exclusive
    gbase[i] = c ? atomicAdd(&gcur[i], c) : 0;
  }
  __syncthreads();

  // local scatter into bucket-sorted LDS staging
#pragma unroll
  for (int k = 0; k < 16; ++k) {
    if (bk[k] >= 0) {
      int r = atomicAdd(&lcur[bk[k]], 1);
      staged[r] = pk[k];
    }
  }
  __syncthreads();

  // copy out: runs per bucket -> near-full-line writes
  for (int i = t; i < n; i += 512) {
    int lo = 0, hi = NB - 1;
    while (lo < hi) {
      int m = (lo + hi + 1) >> 1;
      if (lofs[m] <= i)
        lo = m;
      else
        hi = m - 1;
    }
    st[gbase[lo] + (i - lofs[lo])] = staged[i];
  }
}

// ---------------- GEMM: z = x(Nx128) @ w1(128x64) ----------------

__global__ __launch_bounds__(512) void gemm128_kernel(
    const float* __restrict__ x, const float* __restrict__ w1,
    float* __restrict__ z) {
  __shared__ float w1s[128 * 64];
  __shared__ float rows[8][128 * 4];
  int tid = threadIdx.x;
  for (int i = tid; i < 128 * 64; i += 512) w1s[i] = w1[i];
  __syncthreads();
  const int lane = tid & 63;
  const int wv = tid >> 6;
  float* myrows = rows[wv];
  const int n0 = (blockIdx.x * 8 + wv) * 4;

  float lo[4], hi[4];
#pragma unroll
  for (int j = 0; j < 4; ++j) {
    lo[j] = x[(size_t)(n0 + j) * 128 + lane];
    hi[j] = x[(size_t)(n0 + j) * 128 + 64 + lane];
  }
  *(float4*)&myrows[lane * 4] = make_float4(lo[0], lo[1], lo[2], lo[3]);
  *(float4*)&myrows[(64 + lane) * 4] = make_float4(hi[0], hi[1], hi[2], hi[3]);
  __asm__ volatile("s_waitcnt lgkmcnt(0)" ::: "memory");

  float acc[4] = {0.f, 0.f, 0.f, 0.f};
#pragma unroll 8
  for (int k = 0; k < 128; ++k) {
    float4 r = *(const float4*)&myrows[k * 4];
    float w = w1s[k * 64 + lane];
    acc[0] += r.x * w;
    acc[1] += r.y * w;
    acc[2] += r.z * w;
    acc[3] += r.w * w;
  }
#pragma unroll
  for (int j = 0; j < 4; ++j) z[(size_t)(n0 + j) * 64 + lane] = acc[j];
}

// ---------------- agg: 1 bucket (128 nodes) per block ----------------

template <bool HAS_NEXT>
__global__ __launch_bounds__(512) void agg_kernel(
    const float* __restrict__ zin, const float* __restrict__ b1,
    const float* __restrict__ w2, const float* __restrict__ b2,
    const float* __restrict__ w1n, const float* __restrict__ eps, int li,
    const int* __restrict__ gcur, const int* __restrict__ st,
    float* __restrict__ hout, float* __restrict__ zn) {
  __shared__ float w2s[64 * 64];
  __shared__ float w1ns[HAS_NEXT ? 64 * 64 : 1];
  __shared__ float b1s[64], b2s[64];
  __shared__ float rows[8][256];
  __shared__ int lcol[BCAP];
  __shared__ int lhist[128];
  __shared__ int lofs[129];
  __shared__ int lcur[128];
  __shared__ int ssc[128];
  const int tid = threadIdx.x;
  const int b = blockIdx.x;
  const int base = b << 7;
  const int ofs = b * BCAP;
  const int cnt = min(gcur[b] - ofs, BCAP);

  for (int i = tid; i < 64 * 64; i += 512) {
    w2s[i] = w2[i];
    if (HAS_NEXT) w1ns[i] = w1n[i];
  }
  if (tid < 64) {
    b1s[tid] = b1[tid];
    b2s[tid] = b2[tid];
  }
  if (tid < 128) lhist[tid] = 0;
  __syncthreads();

  // local histogram over 128 dst slots
  for (int i = tid; i < cnt; i += 512) {
    atomicAdd(&lhist[st[ofs + i] & 127], 1);
  }
  __syncthreads();
  if (tid < 128) ssc[tid] = lhist[tid];
  __syncthreads();
  for (int off = 1; off < 128; off <<= 1) {
    int v = (tid < 128 && tid >= off) ? ssc[tid - off] : 0;
    __syncthreads();
    if (tid < 128) ssc[tid] += v;
    __syncthreads();
  }
  if (tid < 128) {
    lofs[tid + 1] = ssc[tid];
    lcur[tid] = ssc[tid] - lhist[tid];
  }
  if (tid == 0) lofs[0] = 0;
  __syncthreads();
  // local CSR fill (LDS scatter)
  for (int i = tid; i < cnt; i += 512) {
    int p = st[ofs + i];
    int r = atomicAdd(&lcur[p & 127], 1);
    lcol[r] = p >> 7;
  }
  __syncthreads();

  const float e1 = 1.0f + eps[li];
  const int lane = tid & 63;
  const int wv = tid >> 6;
  float* myrows = rows[wv];

#pragma unroll 1
  for (int pass = 0; pass < 4; ++pass) {
    const int ln0 = pass * 32 + wv * 4;
    float a[4];
#pragma unroll
    for (int j = 0; j < 4; ++j) {
      int ln = ln0 + j;
      int nn = base + ln;
      int rs = lofs[ln], re = lofs[ln + 1];
      float s0 = 0.f, s1 = 0.f, s2 = 0.f, s3 = 0.f;
      int e = rs;
      for (; e + 4 <= re; e += 4) {
        int c0 = lcol[e], c1 = lcol[e + 1], c2 = lcol[e + 2], c3 = lcol[e + 3];
        s0 += zin[(size_t)c0 * 64 + lane];
        s1 += zin[(size_t)c1 * 64 + lane];
        s2 += zin[(size_t)c2 * 64 + lane];
        s3 += zin[(size_t)c3 * 64 + lane];
      }
      for (; e < re; ++e) s0 += zin[(size_t)lcol[e] * 64 + lane];
      float self = (nn < NNODES) ? zin[(size_t)nn * 64 + lane] : 0.f;
      a[j] = (s0 + s1) + (s2 + s3) + e1 * self;
    }
    float bb = b1s[lane];
#pragma unroll
    for (int j = 0; j < 4; ++j) a[j] = fmaxf(a[j] + bb, 0.f);
    *(float4*)&myrows[lane * 4] = make_float4(a[0], a[1], a[2], a[3]);
    __asm__ volatile("s_waitcnt lgkmcnt(0)" ::: "memory");

    float o[4];
    float b2v = b2s[lane];
#pragma unroll
    for (int j = 0; j < 4; ++j) o[j] = b2v;
#pragma unroll 8
    for (int k = 0; k < 64; ++k) {
      float4 r = *(const float4*)&myrows[k * 4];
      float w = w2s[k * 64 + lane];
      o[0] += r.x * w;
      o[1] += r.y * w;
      o[2] += r.z * w;
      o[3] += r.w * w;
    }
#pragma unroll
    for (int j = 0; j < 4; ++j) {
      o[j] = fmaxf(o[j], 0.f);
      int nn = base + ln0 + j;
      if (nn < NNODES) hout[(size_t)nn * 64 + lane] = o[j];
    }

    if (HAS_NEXT) {
      __asm__ volatile("s_waitcnt lgkmcnt(0)" ::: "memory");
      *(float4*)&myrows[lane * 4] = make_float4(o[0], o[1], o[2], o[3]);
      __asm__ volatile("s_waitcnt lgkmcnt(0)" ::: "memory");
      float q[4] = {0.f, 0.f, 0.f, 0.f};
#pragma unroll 8
      for (int k = 0; k < 64; ++k) {
        float4 r = *(const float4*)&myrows[k * 4];
        float w = w1ns[k * 64 + lane];
        q[0] += r.x * w;
        q[1] += r.y * w;
        q[2] += r.z * w;
        q[3] += r.w * w;
      }
#pragma unroll
      for (int j = 0; j < 4; ++j) {
        int nn = base + ln0 + j;
        if (nn < NNODES) zn[(size_t)nn * 64 + lane] = q[j];
      }
    }
    __asm__ volatile("s_waitcnt lgkmcnt(0)" ::: "memory");
  }
}

// ---------------- Per-graph pooling (batch sorted) ----------------

__device__ __forceinline__ int lower_bound(const int* __restrict__ a, int n,
                                           int v) {
  int lo = 0, hi = n;
  while (lo < hi) {
    int m = (lo + hi) >> 1;
    if (a[m] < v)
      lo = m + 1;
    else
      hi = m;
  }
  return lo;
}

__global__ __launch_bounds__(256) void pool_kernel(const float* __restrict__ h,
                                                   const int* __restrict__ batch,
                                                   float* __restrict__ g,
                                                   int li) {
  int gi = blockIdx.x;
  int tid = threadIdx.x;
  int sub = tid >> 6, f = tid & 63;
  int s = lower_bound(batch, NNODES, gi);
  int e = lower_bound(batch, NNODES, gi + 1);
  float sum = 0.f, mx = -3.0e38f;
  for (int n = s + sub; n < e; n += 4) {
    float v = h[(size_t)n * 64 + f];
    sum += v;
    mx = fmaxf(mx, v);
  }
  __shared__ float ssum[4][64];
  __shared__ float smax[4][64];
  ssum[sub][f] = sum;
  smax[sub][f] = mx;
  __syncthreads();
  if (tid < 64) {
    float S = ssum[0][f] + ssum[1][f] + ssum[2][f] + ssum[3][f];
    float M = fmaxf(fmaxf(smax[0][f], smax[1][f]), fmaxf(smax[2][f], smax[3][f]));
    int cnt = e - s;
    float mean = S / fmaxf((float)cnt, 1.0f);
    int base = gi * 576 + li * 64 + f;
    g[base] = mean;
    g[base + 192] = M;
    g[base + 384] = S;
  }
}

// ---------------- Head ----------------

__global__ __launch_bounds__(256) void head_kernel(
    const float* __restrict__ g, const float* __restrict__ fc1w,
    const float* __restrict__ fc1b, const float* __restrict__ fc2w,
    const float* __restrict__ fc2b, float* __restrict__ out) {
  __shared__ float gs[4 * 576];
  int tid = threadIdx.x;
  int g0 = blockIdx.x * 4;
  for (int i = tid; i < 4 * 576; i += 256) gs[i] = g[g0 * 576 + i];
  __syncthreads();
  int wv = tid >> 6, lane = tid & 63;
  int gi = g0 + wv;
  const float* grow = &gs[wv * 576];
  float acc = fc1b[lane];
#pragma unroll 8
  for (int k = 0; k < 576; ++k) acc += grow[k] * fc1w[k * 64 + lane];
  acc = fmaxf(acc, 0.f);
  float p0 = acc * fc2w[lane * 2 + 0];
  float p1 = acc * fc2w[lane * 2 + 1];
  for (int off = 32; off; off >>= 1) {
    p0 += __shfl_down(p0, off);
    p1 += __shfl_down(p1, off);
  }
  if (lane == 0) {
    out[gi * 2 + 0] = 1.f / (1.f + __expf(-(p0 + fc2b[0])));
    out[gi * 2 + 1] = 1.f / (1.f + __expf(-(p1 + fc2b[1])));
  }
}

// ---------------- launch ----------------

extern "C" void kernel_launch(void* const* d_in, const int* in_sizes, int n_in,
                              void* d_out, int out_size, void* d_ws,
                              size_t ws_size, hipStream_t stream) {
  const float* x = (const float*)d_in[0];
  const int* ei = (const int*)d_in[1];
  const int* src = ei;
  const int* dst = ei + NEDGES;
  const int* batch = (const int*)d_in[2];
  const float* lw1[3] = {(const float*)d_in[3], (const float*)d_in[7],
                         (const float*)d_in[11]};
  const float* lb1[3] = {(const float*)d_in[4], (const float*)d_in[8],
                         (const float*)d_in[12]};
  const float* lw2[3] = {(const float*)d_in[5], (const float*)d_in[9],
                         (const float*)d_in[13]};
  const float* lb2[3] = {(const float*)d_in[6], (const float*)d_in[10],
                         (const float*)d_in[14]};
  const float* eps = (const float*)d_in[15];
  const float* fc1w = (const float*)d_in[16];
  const float* fc1b = (const float*)d_in[17];
  const float* fc2w = (const float*)d_in[18];
  const float* fc2b = (const float*)d_in[19];
  float* out = (float*)d_out;

  char* p = (char*)d_ws;
  auto carve = [&](size_t bytes) {
    void* r = (void*)p;
    p += (bytes + 1023) & ~(size_t)1023;
    return r;
  };
  int* gcur = (int*)carve((NB + 4) * 4);
  int* st = (int*)carve((size_t)NB * BCAP * 4);
  float* zA = (float*)carve((size_t)NNODES * 64 * 4);
  float* zB = (float*)carve((size_t)NNODES * 64 * 4);
  float* hA = (float*)carve((size_t)NNODES * 64 * 4);
  float* g = (float*)carve((size_t)NGRAPHS * 576 * 4);

  init_gcur<<<(NB + 255) / 256, 256, 0, stream>>>(gcur);
  bin_kernel<<<NCHUNKS, 512, 0, stream>>>(src, dst, gcur, st);

  gemm128_kernel<<<3125, 512, 0, stream>>>(x, lw1[0], zA);

  agg_kernel<true><<<NB, 512, 0, stream>>>(zA, lb1[0], lw2[0], lb2[0], lw1[1],
                                           eps, 0, gcur, st, hA, zB);
  pool_kernel<<<NGRAPHS, 256, 0, stream>>>(hA, batch, g, 0);

  agg_kernel<true><<<NB, 512, 0, stream>>>(zB, lb1[1], lw2[1], lb2[1], lw1[2],
                                           eps, 1, gcur, st, hA, zA);
  pool_kernel<<<NGRAPHS, 256, 0, stream>>>(hA, batch, g, 1);

  agg_kernel<false><<<NB, 512, 0, stream>>>(zA, lb1[2], lw2[2], lb2[2],
                                            (const float*)nullptr, eps, 2, gcur,
                                            st, hA, (float*)nullptr);
  pool_kernel<<<NGRAPHS, 256, 0, stream>>>(hA, batch, g, 2);

  head_kernel<<<NGRAPHS / 4, 256, 0, stream>>>(g, fc1w, fc1b, fc2w, fc2b, out);
}